// Round 2
// 230.532 us; speedup vs baseline: 1.0152x; 1.0152x over previous
//
#include <hip/hip_runtime.h>
#include <cmath>

// LocalHolder2D: out = w3*log10(maxpool3(x)) + w5*log10(maxpool5(x)) + w7*log10(maxpool7(x))
// x: (8,64,256,256) fp32, strictly positive => -inf padding == 0 padding.
// Separable maxpool; one wave = one 256-wide row (64 lanes x float4).
//
// R1-R8 (prev session): DPP lane exchange, asm loads, 4-deep SW pipeline -> 82us
//   kernel, VALUBusy 23%, HBM 35%. Stall-bound: wait4 drains prev NT stores
//   (FIFO-coupled) every chunk; only 4 loads in flight, bursty.
// R9 (retry; prior attempt hit infra failure, no verdict): store-decoupled
//   FIFO. Wave = 8-row strip; ALL 14 input rows issued before any store ->
//   FIFO is [14 loads][stores...]. Two counted waits vmcnt(4) retire loads
//   only; NT stores are never waited (still in flight at s_endpgm, which is
//   architecturally fine). 14 KB MLP per wave (was 4 KB bursty). 1-wave
//   blocks (16384 x 64thr) for fine-grained scheduling; __launch_bounds__(64,4)
//   caps VGPR at 128 (est ~100 live: 56 landing regs + ~35 compute temps).

#define IMG_H 256
#define IMG_W 256
#define RPW   8     // output rows per wave
#define NR    14    // input rows per wave = RPW + 6

typedef float vf4 __attribute__((ext_vector_type(4)));

// volatile asm load: compiler cannot sink/reorder it; issues exactly where
// placed. saddr form: mem[s[base] + voff].
__device__ __forceinline__ vf4 aload(const float* base, uint32_t voff) {
  vf4 r;
  asm volatile("global_load_dwordx4 %0, %1, %2"
               : "=v"(r) : "v"(voff), "s"(base) : "memory");
  return r;
}

// After 14 loads issued (FIFO: L0..L13), vmcnt(4) => L0..L9 retired.
// "+v" ties force all consumers of the first 10 rows after the wait.
__device__ __forceinline__ void wait_first10(vf4& a, vf4& b, vf4& c, vf4& d,
                                             vf4& e, vf4& f, vf4& g, vf4& h,
                                             vf4& i, vf4& j) {
  asm volatile("s_waitcnt vmcnt(4)"
               : "+v"(a), "+v"(b), "+v"(c), "+v"(d), "+v"(e),
                 "+v"(f), "+v"(g), "+v"(h), "+v"(i), "+v"(j) :: "memory");
}

// FIFO here: [L10..L13][S0..S3] = 8 outstanding; vmcnt(4) retires exactly
// the 4 loads, leaves the 4 NT stores in flight. Stores never gate.
__device__ __forceinline__ void wait_last4(vf4& a, vf4& b, vf4& c, vf4& d) {
  asm volatile("s_waitcnt vmcnt(4)"
               : "+v"(a), "+v"(b), "+v"(c), "+v"(d) :: "memory");
}

// lane i <- lane i-1, zero at lane 0  (DPP wf_shr1; invalid lane -> old=0)
__device__ __forceinline__ float dpp_left(float v) {
  return __int_as_float(
      __builtin_amdgcn_update_dpp(0, __float_as_int(v), 0x138, 0xF, 0xF, true));
}
// lane i <- lane i+1, zero at lane 63 (DPP wf_shl1)
__device__ __forceinline__ float dpp_right(float v) {
  return __int_as_float(
      __builtin_amdgcn_update_dpp(0, __float_as_int(v), 0x130, 0xF, 0xF, true));
}

__device__ __forceinline__ vf4 vmax(vf4 a, vf4 b) {
  vf4 r;
  r.x = fmaxf(a.x, b.x); r.y = fmaxf(a.y, b.y);
  r.z = fmaxf(a.z, b.z); r.w = fmaxf(a.w, b.w);
  return r;
}

struct PS { float p1, p2, p3, s1, s2, s3, f; };

__device__ __forceinline__ PS make_ps(vf4 a) {
  PS r;
  r.p1 = a.x;
  r.p2 = fmaxf(a.x, a.y);
  r.p3 = fmaxf(r.p2, a.z);
  r.s1 = a.w;
  r.s2 = fmaxf(a.z, a.w);
  r.s3 = fmaxf(a.y, r.s2);
  r.f  = fmaxf(r.p2, r.s2);
  return r;
}

// One output row from its 7-row input window (vertical max -> in-lane
// prefix/suffix + DPP neighbor exchange for horizontal max -> 3x log2).
__device__ __forceinline__ vf4 row_out(vf4 wm3, vf4 wm2, vf4 wm1, vf4 wc,
                                       vf4 wp1, vf4 wp2, vf4 wp3,
                                       float w3, float w5, float w7) {
  vf4 v1 = vmax(vmax(wm1, wc), wp1);
  vf4 v2 = vmax(v1, vmax(wm2, wp2));
  vf4 v3 = vmax(v2, vmax(wm3, wp3));

  PS a1 = make_ps(v1), a2 = make_ps(v2), a3 = make_ps(v3);

  float L1s1 = dpp_left(a1.s1);
  float L2s1 = dpp_left(a2.s1);
  float L2s2 = dpp_left(a2.s2);
  float L3s1 = dpp_left(a3.s1);
  float L3s2 = dpp_left(a3.s2);
  float L3s3 = dpp_left(a3.s3);

  float R1p1 = dpp_right(a1.p1);
  float R2p1 = dpp_right(a2.p1);
  float R2p2 = dpp_right(a2.p2);
  float R3p1 = dpp_right(a3.p1);
  float R3p2 = dpp_right(a3.p2);
  float R3p3 = dpp_right(a3.p3);

  float m3_0 = fmaxf(L1s1, a1.p2);
  float m3_1 = a1.p3;
  float m3_2 = a1.s3;
  float m3_3 = fmaxf(a1.s2, R1p1);

  float m5_0 = fmaxf(L2s2, a2.p3);
  float m5_1 = fmaxf(L2s1, a2.f);
  float m5_2 = fmaxf(a2.f, R2p1);
  float m5_3 = fmaxf(a2.s3, R2p2);

  float m7_0 = fmaxf(L3s3, a3.f);
  float m7_1 = fmaxf(fmaxf(L3s2, a3.f), R3p1);
  float m7_2 = fmaxf(fmaxf(L3s1, a3.f), R3p2);
  float m7_3 = fmaxf(a3.f, R3p3);

  vf4 o;
  o.x = fmaf(w7, __log2f(m7_0), fmaf(w5, __log2f(m5_0), w3 * __log2f(m3_0)));
  o.y = fmaf(w7, __log2f(m7_1), fmaf(w5, __log2f(m5_1), w3 * __log2f(m3_1)));
  o.z = fmaf(w7, __log2f(m7_2), fmaf(w5, __log2f(m5_2), w3 * __log2f(m3_2)));
  o.w = fmaf(w7, __log2f(m7_3), fmaf(w5, __log2f(m5_3), w3 * __log2f(m3_3)));
  return o;
}

__global__ __launch_bounds__(64, 4) void holder_kernel(
    const float* __restrict__ x, float* __restrict__ out,
    float w3, float w5, float w7)
{
  const int lane = threadIdx.x;       // 64-thread block = one wave
  const int band = blockIdx.x;        // 0..31  (band-major: adjacent bands
  const int img  = blockIdx.y;        // 0..511  dispatched consecutively)
  const int r0   = band * RPW;

  const float* px = x + (size_t)img * (IMG_H * IMG_W);       // base (SGPR)
  float*       po = out + (size_t)img * (IMG_H * IMG_W) + lane * 4;
  const uint32_t lo = (uint32_t)lane * 16u;                  // byte off in row

  const vf4 vzero = (vf4)0.0f;

  // ---- issue ALL 14 input-row loads up front (rows r0-3 .. r0+10, clamped)
  vf4 w[NR];
#pragma unroll
  for (int i = 0; i < NR; ++i) {
    int rr = r0 - 3 + i;
    int rc = rr < 0 ? 0 : (rr > IMG_H - 1 ? IMG_H - 1 : rr);
    w[i] = aload(px, (uint32_t)(rc * IMG_W * 4) + lo);
  }

  // ---- rows 0..9 landed; zero-fix above-image rows (only band 0; rows 0..9
  //      can never run past the bottom since r0+6 <= 254)
  wait_first10(w[0], w[1], w[2], w[3], w[4], w[5], w[6], w[7], w[8], w[9]);
#pragma unroll
  for (int i = 0; i < 10; ++i) {
    if (r0 - 3 + i < 0) w[i] = vzero;
  }

  // ---- compute + store output rows r0 .. r0+3
#pragma unroll
  for (int j = 0; j < 4; ++j) {
    vf4 o = row_out(w[j], w[j + 1], w[j + 2], w[j + 3],
                    w[j + 4], w[j + 5], w[j + 6], w3, w5, w7);
    __builtin_nontemporal_store(o, (vf4*)(po + (r0 + j) * IMG_W));
  }

  // ---- rows 10..13 landed (stores untouched); zero-fix below-image rows
  //      (only band 31: rows 256..258 -> w[11..13])
  wait_last4(w[10], w[11], w[12], w[13]);
#pragma unroll
  for (int i = 10; i < NR; ++i) {
    if (r0 - 3 + i >= IMG_H) w[i] = vzero;
  }

  // ---- compute + store output rows r0+4 .. r0+7; stores left in flight
#pragma unroll
  for (int j = 4; j < 8; ++j) {
    vf4 o = row_out(w[j], w[j + 1], w[j + 2], w[j + 3],
                    w[j + 4], w[j + 5], w[j + 6], w3, w5, w7);
    __builtin_nontemporal_store(o, (vf4*)(po + (r0 + j) * IMG_W));
  }
}

extern "C" void kernel_launch(void* const* d_in, const int* in_sizes, int n_in,
                              void* d_out, int out_size, void* d_ws, size_t ws_size,
                              hipStream_t stream) {
  const float* x = (const float*)d_in[0];
  float* out = (float*)d_out;

  const int n_img = in_sizes[0] / (IMG_H * IMG_W);  // B*C = 512

  // closed-form OLS slope weights (H*W cancels in centering), log10(2) folded in
  const double l0 = log10(3.0), l1 = log10(5.0), l2 = log10(7.0);
  const double m  = (l0 + l1 + l2) / 3.0;
  const double c0 = l0 - m, c1 = l1 - m, c2 = l2 - m;
  const double s  = c0 * c0 + c1 * c1 + c2 * c2;
  const double LG2 = 0.30102999566398119521;  // log10(2)
  const float w3 = (float)(c0 / s * LG2);
  const float w5 = (float)(c1 / s * LG2);
  const float w7 = (float)(c2 / s * LG2);

  hipLaunchKernelGGL(holder_kernel, dim3(IMG_H / RPW, n_img), dim3(64), 0,
                     stream, x, out, w3, w5, w7);
}

// Round 3
// 228.940 us; speedup vs baseline: 1.0223x; 1.0070x over previous
//
#include <hip/hip_runtime.h>
#include <cmath>

// LocalHolder2D: out = w3*log10(maxpool3(x)) + w5*log10(maxpool5(x)) + w7*log10(maxpool7(x))
// x: (8,64,256,256) fp32, strictly positive => -inf padding == 0 padding.
// Separable maxpool; one wave = one 256-wide row (64 lanes x float4).
//
// R1-R8 (prev session): DPP lane exchange, asm loads, 4-deep SW pipeline -> 82us
//   kernel, VALUBusy 23%, HBM 35%.
// R9: store-decoupled FIFO, 14-deep load MLP, 1-wave blocks -> 80.7us. NEUTRAL.
//   VALUBusy pinned at 23% across two totally different load structures =>
//   NOT read-latency/MLP-bound.
// R10 (this): A/B the WRITE path. Both prior kernels share NT stores (134 MB
//   bypassing L2 straight to HBM). fillBuffer (cached stores) sustains
//   6.7 TB/s on this chip; we plateau at 3.1 TB/s total. Theory: NT write
//   stream interleaved with demand reads costs ~2-3x at the HBM controller
//   (read/write turnaround, lost burst efficiency) => controller saturated
//   => the invariant 80us wall. Swap NT stores for regular cached stores
//   (L2 write-back bursts, same path as fillBuffer). Everything else
//   identical. Counted-vmcnt FIFO logic unchanged (stores are newest in
//   FIFO; vmcnt(4) still retires loads only).

#define IMG_H 256
#define IMG_W 256
#define RPW   8     // output rows per wave
#define NR    14    // input rows per wave = RPW + 6

typedef float vf4 __attribute__((ext_vector_type(4)));

// volatile asm load: compiler cannot sink/reorder it; issues exactly where
// placed. saddr form: mem[s[base] + voff].
__device__ __forceinline__ vf4 aload(const float* base, uint32_t voff) {
  vf4 r;
  asm volatile("global_load_dwordx4 %0, %1, %2"
               : "=v"(r) : "v"(voff), "s"(base) : "memory");
  return r;
}

// After 14 loads issued (FIFO: L0..L13), vmcnt(4) => L0..L9 retired.
// "+v" ties force all consumers of the first 10 rows after the wait.
__device__ __forceinline__ void wait_first10(vf4& a, vf4& b, vf4& c, vf4& d,
                                             vf4& e, vf4& f, vf4& g, vf4& h,
                                             vf4& i, vf4& j) {
  asm volatile("s_waitcnt vmcnt(4)"
               : "+v"(a), "+v"(b), "+v"(c), "+v"(d), "+v"(e),
                 "+v"(f), "+v"(g), "+v"(h), "+v"(i), "+v"(j) :: "memory");
}

// FIFO here: [L10..L13][S0..S3] = 8 outstanding; vmcnt(4) retires exactly
// the 4 loads (in-order retirement accounting), stores stay in flight.
__device__ __forceinline__ void wait_last4(vf4& a, vf4& b, vf4& c, vf4& d) {
  asm volatile("s_waitcnt vmcnt(4)"
               : "+v"(a), "+v"(b), "+v"(c), "+v"(d) :: "memory");
}

// lane i <- lane i-1, zero at lane 0  (DPP wf_shr1; invalid lane -> old=0)
__device__ __forceinline__ float dpp_left(float v) {
  return __int_as_float(
      __builtin_amdgcn_update_dpp(0, __float_as_int(v), 0x138, 0xF, 0xF, true));
}
// lane i <- lane i+1, zero at lane 63 (DPP wf_shl1)
__device__ __forceinline__ float dpp_right(float v) {
  return __int_as_float(
      __builtin_amdgcn_update_dpp(0, __float_as_int(v), 0x130, 0xF, 0xF, true));
}

__device__ __forceinline__ vf4 vmax(vf4 a, vf4 b) {
  vf4 r;
  r.x = fmaxf(a.x, b.x); r.y = fmaxf(a.y, b.y);
  r.z = fmaxf(a.z, b.z); r.w = fmaxf(a.w, b.w);
  return r;
}

struct PS { float p1, p2, p3, s1, s2, s3, f; };

__device__ __forceinline__ PS make_ps(vf4 a) {
  PS r;
  r.p1 = a.x;
  r.p2 = fmaxf(a.x, a.y);
  r.p3 = fmaxf(r.p2, a.z);
  r.s1 = a.w;
  r.s2 = fmaxf(a.z, a.w);
  r.s3 = fmaxf(a.y, r.s2);
  r.f  = fmaxf(r.p2, r.s2);
  return r;
}

// One output row from its 7-row input window (vertical max -> in-lane
// prefix/suffix + DPP neighbor exchange for horizontal max -> 3x log2).
__device__ __forceinline__ vf4 row_out(vf4 wm3, vf4 wm2, vf4 wm1, vf4 wc,
                                       vf4 wp1, vf4 wp2, vf4 wp3,
                                       float w3, float w5, float w7) {
  vf4 v1 = vmax(vmax(wm1, wc), wp1);
  vf4 v2 = vmax(v1, vmax(wm2, wp2));
  vf4 v3 = vmax(v2, vmax(wm3, wp3));

  PS a1 = make_ps(v1), a2 = make_ps(v2), a3 = make_ps(v3);

  float L1s1 = dpp_left(a1.s1);
  float L2s1 = dpp_left(a2.s1);
  float L2s2 = dpp_left(a2.s2);
  float L3s1 = dpp_left(a3.s1);
  float L3s2 = dpp_left(a3.s2);
  float L3s3 = dpp_left(a3.s3);

  float R1p1 = dpp_right(a1.p1);
  float R2p1 = dpp_right(a2.p1);
  float R2p2 = dpp_right(a2.p2);
  float R3p1 = dpp_right(a3.p1);
  float R3p2 = dpp_right(a3.p2);
  float R3p3 = dpp_right(a3.p3);

  float m3_0 = fmaxf(L1s1, a1.p2);
  float m3_1 = a1.p3;
  float m3_2 = a1.s3;
  float m3_3 = fmaxf(a1.s2, R1p1);

  float m5_0 = fmaxf(L2s2, a2.p3);
  float m5_1 = fmaxf(L2s1, a2.f);
  float m5_2 = fmaxf(a2.f, R2p1);
  float m5_3 = fmaxf(a2.s3, R2p2);

  float m7_0 = fmaxf(L3s3, a3.f);
  float m7_1 = fmaxf(fmaxf(L3s2, a3.f), R3p1);
  float m7_2 = fmaxf(fmaxf(L3s1, a3.f), R3p2);
  float m7_3 = fmaxf(a3.f, R3p3);

  vf4 o;
  o.x = fmaf(w7, __log2f(m7_0), fmaf(w5, __log2f(m5_0), w3 * __log2f(m3_0)));
  o.y = fmaf(w7, __log2f(m7_1), fmaf(w5, __log2f(m5_1), w3 * __log2f(m3_1)));
  o.z = fmaf(w7, __log2f(m7_2), fmaf(w5, __log2f(m5_2), w3 * __log2f(m3_2)));
  o.w = fmaf(w7, __log2f(m7_3), fmaf(w5, __log2f(m5_3), w3 * __log2f(m3_3)));
  return o;
}

__global__ __launch_bounds__(64, 4) void holder_kernel(
    const float* __restrict__ x, float* __restrict__ out,
    float w3, float w5, float w7)
{
  const int lane = threadIdx.x;       // 64-thread block = one wave
  const int band = blockIdx.x;        // 0..31  (band-major: adjacent bands
  const int img  = blockIdx.y;        // 0..511  dispatched consecutively)
  const int r0   = band * RPW;

  const float* px = x + (size_t)img * (IMG_H * IMG_W);       // base (SGPR)
  float*       po = out + (size_t)img * (IMG_H * IMG_W) + lane * 4;
  const uint32_t lo = (uint32_t)lane * 16u;                  // byte off in row

  const vf4 vzero = (vf4)0.0f;

  // ---- issue ALL 14 input-row loads up front (rows r0-3 .. r0+10, clamped)
  vf4 w[NR];
#pragma unroll
  for (int i = 0; i < NR; ++i) {
    int rr = r0 - 3 + i;
    int rc = rr < 0 ? 0 : (rr > IMG_H - 1 ? IMG_H - 1 : rr);
    w[i] = aload(px, (uint32_t)(rc * IMG_W * 4) + lo);
  }

  // ---- rows 0..9 landed; zero-fix above-image rows (only band 0; rows 0..9
  //      can never run past the bottom since r0+6 <= 254)
  wait_first10(w[0], w[1], w[2], w[3], w[4], w[5], w[6], w[7], w[8], w[9]);
#pragma unroll
  for (int i = 0; i < 10; ++i) {
    if (r0 - 3 + i < 0) w[i] = vzero;
  }

  // ---- compute + store output rows r0 .. r0+3 (regular cached stores:
  //      absorbed by L2, written back in bursts -- the fillBuffer path)
#pragma unroll
  for (int j = 0; j < 4; ++j) {
    vf4 o = row_out(w[j], w[j + 1], w[j + 2], w[j + 3],
                    w[j + 4], w[j + 5], w[j + 6], w3, w5, w7);
    *(vf4*)(po + (r0 + j) * IMG_W) = o;
  }

  // ---- rows 10..13 landed (stores untouched); zero-fix below-image rows
  //      (only band 31: rows 256..258 -> w[11..13])
  wait_last4(w[10], w[11], w[12], w[13]);
#pragma unroll
  for (int i = 10; i < NR; ++i) {
    if (r0 - 3 + i >= IMG_H) w[i] = vzero;
  }

  // ---- compute + store output rows r0+4 .. r0+7; stores left in flight
#pragma unroll
  for (int j = 4; j < 8; ++j) {
    vf4 o = row_out(w[j], w[j + 1], w[j + 2], w[j + 3],
                    w[j + 4], w[j + 5], w[j + 6], w3, w5, w7);
    *(vf4*)(po + (r0 + j) * IMG_W) = o;
  }
}

extern "C" void kernel_launch(void* const* d_in, const int* in_sizes, int n_in,
                              void* d_out, int out_size, void* d_ws, size_t ws_size,
                              hipStream_t stream) {
  const float* x = (const float*)d_in[0];
  float* out = (float*)d_out;

  const int n_img = in_sizes[0] / (IMG_H * IMG_W);  // B*C = 512

  // closed-form OLS slope weights (H*W cancels in centering), log10(2) folded in
  const double l0 = log10(3.0), l1 = log10(5.0), l2 = log10(7.0);
  const double m  = (l0 + l1 + l2) / 3.0;
  const double c0 = l0 - m, c1 = l1 - m, c2 = l2 - m;
  const double s  = c0 * c0 + c1 * c1 + c2 * c2;
  const double LG2 = 0.30102999566398119521;  // log10(2)
  const float w3 = (float)(c0 / s * LG2);
  const float w5 = (float)(c1 / s * LG2);
  const float w7 = (float)(c2 / s * LG2);

  hipLaunchKernelGGL(holder_kernel, dim3(IMG_H / RPW, n_img), dim3(64), 0,
                     stream, x, out, w3, w5, w7);
}